// Round 20
// baseline (104.630 us; speedup 1.0000x reference)
//
#include <hip/hip_runtime.h>
#include <hip/hip_bf16.h>

#define NN   4096
#define FIN  512
#define FOUT 64
#define NH   8
#define ALPHA 0.2f
#define ROWS 128
#define LOG2E 1.4426950408889634f

typedef __attribute__((ext_vector_type(8))) short bf16x8;
typedef __attribute__((ext_vector_type(4))) float f32x4;
typedef __attribute__((ext_vector_type(2))) float f32x2;

__device__ __forceinline__ unsigned short f2bf(float x) {
    unsigned u = __float_as_uint(x);
    return (unsigned short)((u + 0x7fffu + ((u >> 16) & 1u)) >> 16);  // RNE
}

__device__ __forceinline__ unsigned pk2(float a, float b) {
    union { __hip_bfloat162 h2; unsigned u; } cv;
    cv.h2 = __float22bfloat162_rn(float2{a, b});   // low 16 = a (RNE)
    return cv.u;
}

__device__ __forceinline__ bf16x8 u4bf8(uint4 u) {   // scalar union: SROA-safe
    union { uint4 a; bf16x8 b; } cv; cv.a = u; return cv.b;
}

// ---------------------------------------------------------------------------
// KB: adj -> 64-bit masks. (Proven R8 kernel, unchanged.)
// ---------------------------------------------------------------------------
__global__ __launch_bounds__(256) void kb(const int* __restrict__ adj,
                                          unsigned long long* __restrict__ bits) {
    const int wv   = blockIdx.x * 4 + (threadIdx.x >> 6);
    const int lane = threadIdx.x & 63;
    const int base = wv * 32;
    #pragma unroll
    for (int r = 0; r < 4; ++r) {
        int v0 = adj[(size_t)(base + r*8 + 0) * 64 + lane];
        int v1 = adj[(size_t)(base + r*8 + 1) * 64 + lane];
        int v2 = adj[(size_t)(base + r*8 + 2) * 64 + lane];
        int v3 = adj[(size_t)(base + r*8 + 3) * 64 + lane];
        int v4 = adj[(size_t)(base + r*8 + 4) * 64 + lane];
        int v5 = adj[(size_t)(base + r*8 + 5) * 64 + lane];
        int v6 = adj[(size_t)(base + r*8 + 6) * 64 + lane];
        int v7 = adj[(size_t)(base + r*8 + 7) * 64 + lane];
        unsigned long long m0 = __ballot(v0 > 0);
        unsigned long long m1 = __ballot(v1 > 0);
        unsigned long long m2 = __ballot(v2 > 0);
        unsigned long long m3 = __ballot(v3 > 0);
        unsigned long long m4 = __ballot(v4 > 0);
        unsigned long long m5 = __ballot(v5 > 0);
        unsigned long long m6 = __ballot(v6 > 0);
        unsigned long long m7 = __ballot(v7 > 0);
        if (lane == 0) {
            ulonglong2* dst = (ulonglong2*)&bits[base + r*8];
            dst[0] = {m0, m1};
            dst[1] = {m2, m3};
            dst[2] = {m4, m5};
            dst[3] = {m6, m7};
        }
    }
}

// ---------------------------------------------------------------------------
// KW: W[h][k][o] fp32 -> WT[h][o][k] bf16. (R17 kernel, unchanged.)
// ---------------------------------------------------------------------------
__global__ __launch_bounds__(256) void kw(const float* __restrict__ W,
                                          unsigned short* __restrict__ WT) {
    __shared__ unsigned short T[64][72];
    const int t  = threadIdx.x;
    const int h  = blockIdx.x >> 3;
    const int k0 = (blockIdx.x & 7) * 64;
    #pragma unroll
    for (int i = 0; i < 4; ++i) {
        int idx = t + i * 256;               // 0..1023: kk 0..63 x o4 0..15
        int kk = idx >> 4, o4 = (idx & 15) * 4;
        float4 v = *(const float4*)&W[((size_t)h * FIN + k0 + kk) * FOUT + o4];
        T[o4+0][kk] = f2bf(v.x); T[o4+1][kk] = f2bf(v.y);
        T[o4+2][kk] = f2bf(v.z); T[o4+3][kk] = f2bf(v.w);
    }
    __syncthreads();
    #pragma unroll
    for (int i = 0; i < 2; ++i) {
        int c = t + i * 256;                 // 0..511: o = c>>3, kch = (c&7)*8
        int o = c >> 3, kch = (c & 7) * 8;
        *(uint4*)&WT[((size_t)h * 64 + o) * FIN + k0 + kch] =
            *(const uint4*)&T[o][kch];
    }
}

// ---------------------------------------------------------------------------
// KG: Wh = x @ W via bf16 MFMA, zero staging LDS. (R17-exact revert.)
// ---------------------------------------------------------------------------
__global__ __launch_bounds__(256) void kg(const float* __restrict__ x,
                                          const unsigned short* __restrict__ WT,
                                          const float* __restrict__ aw,
                                          unsigned short* __restrict__ WhTs,
                                          float* __restrict__ f1,
                                          float* __restrict__ f2) {
    __shared__ unsigned short Tb[64][80];
    __shared__ float r1[64][16];
    __shared__ float r2[64][16];
    const int t = threadIdx.x, lane = t & 63, wid = t >> 6;
    const int h    = blockIdx.x >> 6;
    const int nti  = blockIdx.x & 63;
    const int row0 = nti * 64;
    const int lrow = wid * 16 + (lane & 15);       // A-frag row (block-local)
    const int kc   = (lane >> 4) * 8;              // k-chunk within 32-step
    const float* xr = x + (size_t)(row0 + lrow) * FIN;
    const unsigned short* WTh = WT + (size_t)h * 64 * FIN;
    f32x4 acc[4] = {};

    #pragma unroll 4
    for (int k0 = 0; k0 < FIN; k0 += 32) {
        float4 xa = *(const float4*)&xr[k0 + kc];
        float4 xb = *(const float4*)&xr[k0 + kc + 4];
        bf16x8 af = u4bf8(uint4{pk2(xa.x, xa.y), pk2(xa.z, xa.w),
                                pk2(xb.x, xb.y), pk2(xb.z, xb.w)});
        #pragma unroll
        for (int cf = 0; cf < 4; ++cf) {
            int o = cf * 16 + (lane & 15);
            bf16x8 bfr = *(const bf16x8*)&WTh[(size_t)o * FIN + k0 + kc];
            acc[cf] = __builtin_amdgcn_mfma_f32_16x16x32_bf16(af, bfr, acc[cf], 0, 0, 0);
        }
    }

    // epilogue: f1/f2 partials + bf16 transpose tile (from C-layout accs)
    float a1v[4], a2v[4];
    #pragma unroll
    for (int cf = 0; cf < 4; ++cf) {
        a1v[cf] = aw[h * 2 * FOUT + cf * 16 + (lane & 15)];
        a2v[cf] = aw[h * 2 * FOUT + FOUT + cf * 16 + (lane & 15)];
    }
    #pragma unroll
    for (int rg = 0; rg < 4; ++rg) {
        const int lr = wid * 16 + (lane >> 4) * 4 + rg;   // C row (block-local)
        float s1 = 0.f, s2 = 0.f;
        #pragma unroll
        for (int cf = 0; cf < 4; ++cf) {
            s1 = fmaf(acc[cf][rg], a1v[cf], s1);
            s2 = fmaf(acc[cf][rg], a2v[cf], s2);
            Tb[cf * 16 + (lane & 15)][lr] = f2bf(acc[cf][rg]);
        }
        r1[lr][lane & 15] = s1;
        r2[lr][lane & 15] = s2;
    }
    __syncthreads();
    if (t < 64) {
        float s1 = 0.f, s2 = 0.f;
        #pragma unroll
        for (int k = 0; k < 16; ++k) { s1 += r1[t][k]; s2 += r2[t][k]; }
        f1[h * NN + row0 + t] = s1 * LOG2E;   // prescale: exp(x)=exp2(x*log2e)
        f2[h * NN + row0 + t] = s2 * LOG2E;
    }
    // write tile in k3's swizzled byte order (pre-swizzled global source)
    unsigned char* tileB = (unsigned char*)(WhTs + ((size_t)(h * 64) + nti) * 4096);
    #pragma unroll
    for (int i = 0; i < 2; ++i) {
        int c = t + i * 256;
        int o = c >> 3, nch = c & 7;
        *(uint4*)(tileB + o * 128 + ((nch * 16) ^ ((o & 7) << 4))) =
            *(const uint4*)&Tb[o][nch * 8];
    }
}

// ---------------------------------------------------------------------------
// K3: fused masked softmax + PV (bf16 MFMA), j-split. R20: 1-BARRIER
// double-buffered loop — fill buf^1 (tile it+1: ds_write Wh + P-compute)
// BEFORE MFMA on buf (tile it); one barrier/tile. P-VALU and MFMA issue on
// separate pipes from the same wave -> intra-wave overlap; barrier drains
// halved. Race-safety: write(buf^1,it) -> barrier -> read(buf^1,it+1);
// read(buf,it) drained by pre-barrier lgkmcnt before write(buf,it+2).
// (Plain ds_write path — R5's race was global_load_lds-specific.)
// ---------------------------------------------------------------------------
__global__ __launch_bounds__(256, 2) void k3_attn(
        const unsigned long long* __restrict__ bits,
        const unsigned short* __restrict__ WhTs,
        const float* __restrict__ f1, const float* __restrict__ f2,
        float* __restrict__ pnum, float* __restrict__ pden) {
    __shared__ unsigned char psB[2][ROWS * 128];   // 2 x 16 KB
    __shared__ unsigned char wsB[2][8192];         // 2 x  8 KB
    const int t    = threadIdx.x;
    const int lane = t & 63, wid = t >> 6;
    const int h    = blockIdx.y;
    const int row0 = blockIdx.x * ROWS;
    const int js   = blockIdx.z, JS = gridDim.z;
    const int ntile = (NN / 64) / JS;
    const int nt0   = js * ntile;
    const int pr   = t >> 1, psub = t & 1;     // row 0..127, j-half 0..1
    const float f1r = f1[h * NN + row0 + pr];
    const float* f2h = f2 + h * NN;
    const unsigned long long* bitsRow = bits + (size_t)(row0 + pr) * 64;
    const unsigned short* WTS = WhTs + (size_t)h * 64 * 4096;
    const int prswz = (pr & 7) << 4;
    f32x4 acc[2][4] = {};
    f32x4 accd[2] = {};
    const bf16x8 ones = {0x3F80, 0x3F80, 0x3F80, 0x3F80,
                         0x3F80, 0x3F80, 0x3F80, 0x3F80};   // bf16 1.0 x8
    const f32x2 f1p = {f1r, f1r};

    uint4 wreg0, wreg1;
    auto loadW = [&](int nti, uint4& w0, uint4& w1) {
        const uint4* gt = (const uint4*)(WTS + (size_t)nti * 4096);
        w0 = gt[t];
        w1 = gt[t + 256];
    };
    // P-compute for tile nti into psB[buf] (R18 math: packed e, exp2, mask)
    auto fillP = [&](int nti, int buf) {
        unsigned msk = (unsigned)(bitsRow[nti] >> (psub << 5));
        const float* f2c = f2h + nti * 64 + psub * 32;
        #pragma unroll
        for (int q = 0; q < 4; ++q) {
            unsigned pk[4];
            #pragma unroll
            for (int c2 = 0; c2 < 2; ++c2) {
                float4 f4 = *(const float4*)&f2c[q * 8 + c2 * 4];
                f32x2 eA = f1p + (f32x2){f4.x, f4.y};   // v_pk_add_f32
                f32x2 eB = f1p + (f32x2){f4.z, f4.w};
                eA = __builtin_elementwise_max(eA, eA * ALPHA);
                eB = __builtin_elementwise_max(eB, eB * ALPHA);
                const int b = q * 8 + c2 * 4;
                float p0 = ((msk >> (b+0)) & 1u) ? __builtin_amdgcn_exp2f(eA.x) : 0.f;
                float p1 = ((msk >> (b+1)) & 1u) ? __builtin_amdgcn_exp2f(eA.y) : 0.f;
                float p2 = ((msk >> (b+2)) & 1u) ? __builtin_amdgcn_exp2f(eB.x) : 0.f;
                float p3 = ((msk >> (b+3)) & 1u) ? __builtin_amdgcn_exp2f(eB.y) : 0.f;
                pk[c2*2+0] = pk2(p0, p1);
                pk[c2*2+1] = pk2(p2, p3);
            }
            uint4 w = {pk[0], pk[1], pk[2], pk[3]};
            *(uint4*)&psB[buf][pr * 128 + ((psub*64 + q*16) ^ prswz)] = w;
        }
    };

    // prologue: stage tile nt0 into buf 0
    loadW(nt0, wreg0, wreg1);
    *(uint4*)&wsB[0][t * 16]        = wreg0;
    *(uint4*)&wsB[0][t * 16 + 4096] = wreg1;
    fillP(nt0, 0);
    if (ntile > 1) loadW(nt0 + 1, wreg0, wreg1);
    __syncthreads();

    const int kb2 = (lane >> 4) * 16;
    for (int it = 0; it < ntile; ++it) {
        const int cur = it & 1;
        // ---- fill buf^1 for tile it+1 (overlaps MFMA below via dual pipes) ----
        if (it + 1 < ntile) {
            *(uint4*)&wsB[cur ^ 1][t * 16]        = wreg0;
            *(uint4*)&wsB[cur ^ 1][t * 16 + 4096] = wreg1;
            fillP(nt0 + it + 1, cur ^ 1);
            if (it + 2 < ntile) loadW(nt0 + it + 2, wreg0, wreg1);
        }
        // ---- MFMA on buf cur (tile it) ----
        #pragma unroll
        for (int fg = 0; fg < 2; ++fg) {
            const int arw  = wid * 32 + fg * 16 + (lane & 15);
            const int aswz = (arw & 7) << 4;
            #pragma unroll
            for (int ks = 0; ks < 2; ++ks) {
                bf16x8 af = *(const bf16x8*)&psB[cur][arw * 128 + ((ks*64 + kb2) ^ aswz)];
                accd[fg] = __builtin_amdgcn_mfma_f32_16x16x32_bf16(af, ones, accd[fg], 0, 0, 0);
                #pragma unroll
                for (int cf = 0; cf < 4; ++cf) {
                    int brw = cf * 16 + (lane & 15);
                    bf16x8 bfr = *(const bf16x8*)&wsB[cur][brw * 128 + ((ks*64 + kb2) ^ ((brw & 7) << 4))];
                    acc[fg][cf] = __builtin_amdgcn_mfma_f32_16x16x32_bf16(af, bfr, acc[fg][cf], 0, 0, 0);
                }
            }
        }
        __syncthreads();   // fill(it+1) complete + MFMA reads(it) drained
    }

    float* pn = pnum + (((size_t)js * NH + h) * NN + row0) * 64;
    #pragma unroll
    for (int fg = 0; fg < 2; ++fg)
        #pragma unroll
        for (int cf = 0; cf < 4; ++cf) {
            int o = cf * 16 + (lane & 15);
            #pragma unroll
            for (int rg = 0; rg < 4; ++rg) {
                int rl = wid * 32 + fg * 16 + (lane >> 4) * 4 + rg;
                pn[(size_t)rl * 64 + o] = acc[fg][cf][rg];
            }
        }
    if ((lane & 15) == 0) {                    // col-0 lanes hold den[row]
        float* pd = pden + ((size_t)js * NH + h) * NN + row0;
        #pragma unroll
        for (int fg = 0; fg < 2; ++fg)
            #pragma unroll
            for (int rg = 0; rg < 4; ++rg)
                pd[wid * 32 + fg * 16 + (lane >> 4) * 4 + rg] = accd[fg][rg];
    }
}

// ---------------------------------------------------------------------------
// K4: reduce over JS slices + normalize.
// ---------------------------------------------------------------------------
__global__ __launch_bounds__(256) void k4_red(const float* __restrict__ pnum,
                                              const float* __restrict__ pden,
                                              float* __restrict__ out, int JS) {
    const int idx = blockIdx.x * 256 + threadIdx.x;   // 0..524287
    const int h   = idx >> 16;
    const int rem = idx & 65535;
    const int n   = rem >> 4;
    const int o4  = (rem & 15) * 4;
    float4 s = {0.f, 0.f, 0.f, 0.f};
    float  d = 0.f;
    for (int js = 0; js < JS; ++js) {
        const float* p = pnum + (((size_t)js * NH + h) * NN + n) * 64 + o4;
        float4 v = *(const float4*)p;
        s.x += v.x; s.y += v.y; s.z += v.z; s.w += v.w;
        d += pden[((size_t)js * NH + h) * NN + n];
    }
    float inv = 1.0f / d;
    float4 r = {s.x * inv, s.y * inv, s.z * inv, s.w * inv};
    *(float4*)&out[(size_t)n * (NH * FOUT) + h * FOUT + o4] = r;
}

extern "C" void kernel_launch(void* const* d_in, const int* in_sizes, int n_in,
                              void* d_out, int out_size, void* d_ws, size_t ws_size,
                              hipStream_t stream) {
    const float* x   = (const float*)d_in[0];
    const int*   adj = (const int*)d_in[1];
    const float* W   = (const float*)d_in[2];
    const float* a   = (const float*)d_in[3];
    float* outp = (float*)d_out;

    // workspace layout
    unsigned short* WhTs = (unsigned short*)d_ws;                   // 4 MB (tiled)
    float* f1 = (float*)(WhTs + (size_t)NH * 64 * NN);              // 128 KB
    float* f2 = f1 + NH * NN;                                       // 128 KB
    unsigned short* WT = (unsigned short*)(f2 + NH * NN);           // 512 KB bf16
    unsigned long long* bits = (unsigned long long*)(WT + (size_t)NH * 64 * FIN); // 2 MB
    float* pnum = (float*)(bits + (size_t)NN * 64);
    const size_t baseBytes  = (size_t)((char*)pnum - (char*)d_ws);
    const size_t sliceBytes = (size_t)NH * NN * 65 * 4;             // num+den per slice
    int JS = 1;
    if      (ws_size >= baseBytes + 4 * sliceBytes) JS = 4;
    else if (ws_size >= baseBytes + 2 * sliceBytes) JS = 2;
    float* pden = pnum + (size_t)JS * NH * NN * 64;

    kb     <<<dim3(2048),            256, 0, stream>>>(adj, bits);
    kw     <<<dim3(64),              256, 0, stream>>>(W, WT);
    kg     <<<dim3(512),             256, 0, stream>>>(x, WT, a, WhTs, f1, f2);
    k3_attn<<<dim3(NN/ROWS, NH, JS), 256, 0, stream>>>(bits, WhTs, f1, f2, pnum, pden);
    k4_red <<<dim3(NN*NH*FOUT/4/256), 256, 0, stream>>>(pnum, pden, outp, JS);
}

// Round 21
// 100.606 us; speedup vs baseline: 1.0400x; 1.0400x over previous
//
#include <hip/hip_runtime.h>
#include <hip/hip_bf16.h>

#define NN   4096
#define FIN  512
#define FOUT 64
#define NH   8
#define ALPHA 0.2f
#define ROWS 128
#define LOG2E 1.4426950408889634f

typedef __attribute__((ext_vector_type(8))) short bf16x8;
typedef __attribute__((ext_vector_type(4))) float f32x4;
typedef __attribute__((ext_vector_type(2))) float f32x2;

__device__ __forceinline__ unsigned short f2bf(float x) {
    unsigned u = __float_as_uint(x);
    return (unsigned short)((u + 0x7fffu + ((u >> 16) & 1u)) >> 16);  // RNE
}

__device__ __forceinline__ unsigned pk2(float a, float b) {
    union { __hip_bfloat162 h2; unsigned u; } cv;
    cv.h2 = __float22bfloat162_rn(float2{a, b});   // low 16 = a (RNE)
    return cv.u;
}

__device__ __forceinline__ bf16x8 u4bf8(uint4 u) {   // scalar union: SROA-safe
    union { uint4 a; bf16x8 b; } cv; cv.a = u; return cv.b;
}

// ---------------------------------------------------------------------------
// KB: adj -> 64-bit masks. (Proven R8 kernel, unchanged.)
// ---------------------------------------------------------------------------
__global__ __launch_bounds__(256) void kb(const int* __restrict__ adj,
                                          unsigned long long* __restrict__ bits) {
    const int wv   = blockIdx.x * 4 + (threadIdx.x >> 6);
    const int lane = threadIdx.x & 63;
    const int base = wv * 32;
    #pragma unroll
    for (int r = 0; r < 4; ++r) {
        int v0 = adj[(size_t)(base + r*8 + 0) * 64 + lane];
        int v1 = adj[(size_t)(base + r*8 + 1) * 64 + lane];
        int v2 = adj[(size_t)(base + r*8 + 2) * 64 + lane];
        int v3 = adj[(size_t)(base + r*8 + 3) * 64 + lane];
        int v4 = adj[(size_t)(base + r*8 + 4) * 64 + lane];
        int v5 = adj[(size_t)(base + r*8 + 5) * 64 + lane];
        int v6 = adj[(size_t)(base + r*8 + 6) * 64 + lane];
        int v7 = adj[(size_t)(base + r*8 + 7) * 64 + lane];
        unsigned long long m0 = __ballot(v0 > 0);
        unsigned long long m1 = __ballot(v1 > 0);
        unsigned long long m2 = __ballot(v2 > 0);
        unsigned long long m3 = __ballot(v3 > 0);
        unsigned long long m4 = __ballot(v4 > 0);
        unsigned long long m5 = __ballot(v5 > 0);
        unsigned long long m6 = __ballot(v6 > 0);
        unsigned long long m7 = __ballot(v7 > 0);
        if (lane == 0) {
            ulonglong2* dst = (ulonglong2*)&bits[base + r*8];
            dst[0] = {m0, m1};
            dst[1] = {m2, m3};
            dst[2] = {m4, m5};
            dst[3] = {m6, m7};
        }
    }
}

// ---------------------------------------------------------------------------
// KW: W[h][k][o] fp32 -> WT[h][o][k] bf16. (R17 kernel, unchanged.)
// ---------------------------------------------------------------------------
__global__ __launch_bounds__(256) void kw(const float* __restrict__ W,
                                          unsigned short* __restrict__ WT) {
    __shared__ unsigned short T[64][72];
    const int t  = threadIdx.x;
    const int h  = blockIdx.x >> 3;
    const int k0 = (blockIdx.x & 7) * 64;
    #pragma unroll
    for (int i = 0; i < 4; ++i) {
        int idx = t + i * 256;               // 0..1023: kk 0..63 x o4 0..15
        int kk = idx >> 4, o4 = (idx & 15) * 4;
        float4 v = *(const float4*)&W[((size_t)h * FIN + k0 + kk) * FOUT + o4];
        T[o4+0][kk] = f2bf(v.x); T[o4+1][kk] = f2bf(v.y);
        T[o4+2][kk] = f2bf(v.z); T[o4+3][kk] = f2bf(v.w);
    }
    __syncthreads();
    #pragma unroll
    for (int i = 0; i < 2; ++i) {
        int c = t + i * 256;                 // 0..511: o = c>>3, kch = (c&7)*8
        int o = c >> 3, kch = (c & 7) * 8;
        *(uint4*)&WT[((size_t)h * 64 + o) * FIN + k0 + kch] =
            *(const uint4*)&T[o][kch];
    }
}

// ---------------------------------------------------------------------------
// KG: Wh = x @ W via bf16 MFMA, zero staging LDS. R19's split geometry
// (1024 blocks x 128 thr, 32-row half-tiles — 4 blocks/CU for this
// latency-bound GEMM; proven correct in R19, now isolated from JS=8).
// ---------------------------------------------------------------------------
__global__ __launch_bounds__(128) void kg(const float* __restrict__ x,
                                          const unsigned short* __restrict__ WT,
                                          const float* __restrict__ aw,
                                          unsigned short* __restrict__ WhTs,
                                          float* __restrict__ f1,
                                          float* __restrict__ f2) {
    __shared__ unsigned short Tb[64][40];   // [o][local row 0..31]
    __shared__ float r1[32][16];
    __shared__ float r2[32][16];
    const int t = threadIdx.x, lane = t & 63, wid = t >> 6;   // 2 waves
    const int bx   = blockIdx.x;              // 0..1023
    const int h    = bx >> 7;
    const int sub  = bx & 127;
    const int nti  = sub >> 1;                // WhTs tile 0..63
    const int half = sub & 1;                 // which 32-row half
    const int row0 = nti * 64 + half * 32;
    const int lrow = wid * 16 + (lane & 15);  // local row 0..31
    const int kc   = (lane >> 4) * 8;         // k-chunk within 32-step
    const float* xr = x + (size_t)(row0 + lrow) * FIN;
    const unsigned short* WTh = WT + (size_t)h * 64 * FIN;
    f32x4 acc[4] = {};

    #pragma unroll 4
    for (int k0 = 0; k0 < FIN; k0 += 32) {
        float4 xa = *(const float4*)&xr[k0 + kc];
        float4 xb = *(const float4*)&xr[k0 + kc + 4];
        bf16x8 af = u4bf8(uint4{pk2(xa.x, xa.y), pk2(xa.z, xa.w),
                                pk2(xb.x, xb.y), pk2(xb.z, xb.w)});
        #pragma unroll
        for (int cf = 0; cf < 4; ++cf) {
            int o = cf * 16 + (lane & 15);
            bf16x8 bfr = *(const bf16x8*)&WTh[(size_t)o * FIN + k0 + kc];
            acc[cf] = __builtin_amdgcn_mfma_f32_16x16x32_bf16(af, bfr, acc[cf], 0, 0, 0);
        }
    }

    // epilogue: f1/f2 partials + bf16 transpose tile (from C-layout accs)
    float a1v[4], a2v[4];
    #pragma unroll
    for (int cf = 0; cf < 4; ++cf) {
        a1v[cf] = aw[h * 2 * FOUT + cf * 16 + (lane & 15)];
        a2v[cf] = aw[h * 2 * FOUT + FOUT + cf * 16 + (lane & 15)];
    }
    #pragma unroll
    for (int rg = 0; rg < 4; ++rg) {
        const int lr = wid * 16 + (lane >> 4) * 4 + rg;   // local C row 0..31
        float s1 = 0.f, s2 = 0.f;
        #pragma unroll
        for (int cf = 0; cf < 4; ++cf) {
            s1 = fmaf(acc[cf][rg], a1v[cf], s1);
            s2 = fmaf(acc[cf][rg], a2v[cf], s2);
            Tb[cf * 16 + (lane & 15)][lr] = f2bf(acc[cf][rg]);
        }
        r1[lr][lane & 15] = s1;
        r2[lr][lane & 15] = s2;
    }
    __syncthreads();
    if (t < 32) {
        float s1 = 0.f, s2 = 0.f;
        #pragma unroll
        for (int k = 0; k < 16; ++k) { s1 += r1[t][k]; s2 += r2[t][k]; }
        f1[h * NN + row0 + t] = s1 * LOG2E;   // prescale: exp(x)=exp2(x*log2e)
        f2[h * NN + row0 + t] = s2 * LOG2E;
    }
    // write this half's chunks of the tile in k3's swizzled byte order
    unsigned char* tileB = (unsigned char*)(WhTs + ((size_t)(h * 64) + nti) * 4096);
    #pragma unroll
    for (int i = 0; i < 2; ++i) {
        int c = t + i * 128;                 // 0..255: o = c>>2, q = c&3
        int o = c >> 2, q = c & 3;
        *(uint4*)(tileB + o * 128 + (((half * 64 + q * 16)) ^ ((o & 7) << 4))) =
            *(const uint4*)&Tb[o][q * 8];
    }
}

// ---------------------------------------------------------------------------
// K3: fused masked softmax + PV (bf16 MFMA), j-split. R18-EXACT revert
// (61.3 us, reproduced 3x — the plateau of this structure): 2-barrier
// template, 256 thr, ROWS=128, packed-f32 e-math, ones-B denominator MFMA,
// Wh register-prefetch, JS=4.
// ---------------------------------------------------------------------------
__global__ __launch_bounds__(256, 4) void k3_attn(
        const unsigned long long* __restrict__ bits,
        const unsigned short* __restrict__ WhTs,
        const float* __restrict__ f1, const float* __restrict__ f2,
        float* __restrict__ pnum, float* __restrict__ pden) {
    __shared__ unsigned char psB[ROWS * 128];   // 16 KB
    __shared__ unsigned char wsB[8192];         //  8 KB
    const int t    = threadIdx.x;
    const int lane = t & 63, wid = t >> 6;
    const int h    = blockIdx.y;
    const int row0 = blockIdx.x * ROWS;
    const int js   = blockIdx.z, JS = gridDim.z;
    const int ntile = (NN / 64) / JS;
    const int nt0   = js * ntile;
    const int pr   = t >> 1, psub = t & 1;     // row 0..127, j-half 0..1
    const float f1r = f1[h * NN + row0 + pr];
    const float* f2h = f2 + h * NN;
    const unsigned long long* bitsRow = bits + (size_t)(row0 + pr) * 64;
    const unsigned short* WTS = WhTs + (size_t)h * 64 * 4096;
    const int prswz = (pr & 7) << 4;
    f32x4 acc[2][4] = {};
    f32x4 accd[2] = {};
    const bf16x8 ones = {0x3F80, 0x3F80, 0x3F80, 0x3F80,
                         0x3F80, 0x3F80, 0x3F80, 0x3F80};   // bf16 1.0 x8
    const f32x2 f1p = {f1r, f1r};

    uint4 wreg0, wreg1;
    auto loadW = [&](int nti, uint4& w0, uint4& w1) {
        const uint4* gt = (const uint4*)(WTS + (size_t)nti * 4096);
        w0 = gt[t];
        w1 = gt[t + 256];
    };
    loadW(nt0, wreg0, wreg1);

    const int kb2 = (lane >> 4) * 16;
    for (int it = 0; it < ntile; ++it) {
        const int nti = nt0 + it;
        __syncthreads();                       // prev MFMA done reading tiles
        *(uint4*)&wsB[t * 16]        = wreg0;
        *(uint4*)&wsB[t * 16 + 4096] = wreg1;
        {
            unsigned msk = (unsigned)(bitsRow[nti] >> (psub << 5));
            const float* f2c = f2h + nti * 64 + psub * 32;
            #pragma unroll
            for (int q = 0; q < 4; ++q) {
                unsigned pk[4];
                #pragma unroll
                for (int c2 = 0; c2 < 2; ++c2) {
                    float4 f4 = *(const float4*)&f2c[q * 8 + c2 * 4];
                    f32x2 eA = f1p + (f32x2){f4.x, f4.y};   // v_pk_add_f32
                    f32x2 eB = f1p + (f32x2){f4.z, f4.w};
                    eA = __builtin_elementwise_max(eA, eA * ALPHA);  // pk_mul+pk_max
                    eB = __builtin_elementwise_max(eB, eB * ALPHA);
                    const int b = q * 8 + c2 * 4;
                    float p0 = ((msk >> (b+0)) & 1u) ? __builtin_amdgcn_exp2f(eA.x) : 0.f;
                    float p1 = ((msk >> (b+1)) & 1u) ? __builtin_amdgcn_exp2f(eA.y) : 0.f;
                    float p2 = ((msk >> (b+2)) & 1u) ? __builtin_amdgcn_exp2f(eB.x) : 0.f;
                    float p3 = ((msk >> (b+3)) & 1u) ? __builtin_amdgcn_exp2f(eB.y) : 0.f;
                    pk[c2*2+0] = pk2(p0, p1);
                    pk[c2*2+1] = pk2(p2, p3);
                }
                uint4 w = {pk[0], pk[1], pk[2], pk[3]};
                *(uint4*)&psB[pr * 128 + ((psub*64 + q*16) ^ prswz)] = w;
            }
        }
        if (it + 1 < ntile) loadW(nti + 1, wreg0, wreg1);
        __syncthreads();                       // tiles visible
        #pragma unroll
        for (int fg = 0; fg < 2; ++fg) {
            const int arw  = wid * 32 + fg * 16 + (lane & 15);
            const int aswz = (arw & 7) << 4;
            #pragma unroll
            for (int ks = 0; ks < 2; ++ks) {
                bf16x8 af = *(const bf16x8*)&psB[arw * 128 + ((ks*64 + kb2) ^ aswz)];
                accd[fg] = __builtin_amdgcn_mfma_f32_16x16x32_bf16(af, ones, accd[fg], 0, 0, 0);
                #pragma unroll
                for (int cf = 0; cf < 4; ++cf) {
                    int brw = cf * 16 + (lane & 15);
                    bf16x8 bfr = *(const bf16x8*)&wsB[brw * 128 + ((ks*64 + kb2) ^ ((brw & 7) << 4))];
                    acc[fg][cf] = __builtin_amdgcn_mfma_f32_16x16x32_bf16(af, bfr, acc[fg][cf], 0, 0, 0);
                }
            }
        }
    }

    float* pn = pnum + (((size_t)js * NH + h) * NN + row0) * 64;
    #pragma unroll
    for (int fg = 0; fg < 2; ++fg)
        #pragma unroll
        for (int cf = 0; cf < 4; ++cf) {
            int o = cf * 16 + (lane & 15);
            #pragma unroll
            for (int rg = 0; rg < 4; ++rg) {
                int rl = wid * 32 + fg * 16 + (lane >> 4) * 4 + rg;
                pn[(size_t)rl * 64 + o] = acc[fg][cf][rg];
            }
        }
    if ((lane & 15) == 0) {                    // col-0 lanes hold den[row]
        float* pd = pden + ((size_t)js * NH + h) * NN + row0;
        #pragma unroll
        for (int fg = 0; fg < 2; ++fg)
            #pragma unroll
            for (int rg = 0; rg < 4; ++rg)
                pd[wid * 32 + fg * 16 + (lane >> 4) * 4 + rg] = accd[fg][rg];
    }
}

// ---------------------------------------------------------------------------
// K4: reduce over JS slices + normalize.
// ---------------------------------------------------------------------------
__global__ __launch_bounds__(256) void k4_red(const float* __restrict__ pnum,
                                              const float* __restrict__ pden,
                                              float* __restrict__ out, int JS) {
    const int idx = blockIdx.x * 256 + threadIdx.x;   // 0..524287
    const int h   = idx >> 16;
    const int rem = idx & 65535;
    const int n   = rem >> 4;
    const int o4  = (rem & 15) * 4;
    float4 s = {0.f, 0.f, 0.f, 0.f};
    float  d = 0.f;
    for (int js = 0; js < JS; ++js) {
        const float* p = pnum + (((size_t)js * NH + h) * NN + n) * 64 + o4;
        float4 v = *(const float4*)p;
        s.x += v.x; s.y += v.y; s.z += v.z; s.w += v.w;
        d += pden[((size_t)js * NH + h) * NN + n];
    }
    float inv = 1.0f / d;
    float4 r = {s.x * inv, s.y * inv, s.z * inv, s.w * inv};
    *(float4*)&out[(size_t)n * (NH * FOUT) + h * FOUT + o4] = r;
}

extern "C" void kernel_launch(void* const* d_in, const int* in_sizes, int n_in,
                              void* d_out, int out_size, void* d_ws, size_t ws_size,
                              hipStream_t stream) {
    const float* x   = (const float*)d_in[0];
    const int*   adj = (const int*)d_in[1];
    const float* W   = (const float*)d_in[2];
    const float* a   = (const float*)d_in[3];
    float* outp = (float*)d_out;

    // workspace layout
    unsigned short* WhTs = (unsigned short*)d_ws;                   // 4 MB (tiled)
    float* f1 = (float*)(WhTs + (size_t)NH * 64 * NN);              // 128 KB
    float* f2 = f1 + NH * NN;                                       // 128 KB
    unsigned short* WT = (unsigned short*)(f2 + NH * NN);           // 512 KB bf16
    unsigned long long* bits = (unsigned long long*)(WT + (size_t)NH * 64 * FIN); // 2 MB
    float* pnum = (float*)(bits + (size_t)NN * 64);
    const size_t baseBytes  = (size_t)((char*)pnum - (char*)d_ws);
    const size_t sliceBytes = (size_t)NH * NN * 65 * 4;             // num+den per slice
    int JS = 1;
    if      (ws_size >= baseBytes + 4 * sliceBytes) JS = 4;
    else if (ws_size >= baseBytes + 2 * sliceBytes) JS = 2;
    float* pden = pnum + (size_t)JS * NH * NN * 64;

    kb     <<<dim3(2048),            256, 0, stream>>>(adj, bits);
    kw     <<<dim3(64),              256, 0, stream>>>(W, WT);
    kg     <<<dim3(1024),            128, 0, stream>>>(x, WT, a, WhTs, f1, f2);
    k3_attn<<<dim3(NN/ROWS, NH, JS), 256, 0, stream>>>(bits, WhTs, f1, f2, pnum, pden);
    k4_red <<<dim3(NN*NH*FOUT/4/256), 256, 0, stream>>>(pnum, pden, outp, JS);
}

// Round 22
// 95.970 us; speedup vs baseline: 1.0902x; 1.0483x over previous
//
#include <hip/hip_runtime.h>
#include <hip/hip_bf16.h>

#define NN   4096
#define FIN  512
#define FOUT 64
#define NH   8
#define ALPHA 0.2f
#define ROWS 128
#define LOG2E 1.4426950408889634f

typedef __attribute__((ext_vector_type(8))) short bf16x8;
typedef __attribute__((ext_vector_type(4))) float f32x4;
typedef __attribute__((ext_vector_type(2))) float f32x2;

__device__ __forceinline__ unsigned short f2bf(float x) {
    unsigned u = __float_as_uint(x);
    return (unsigned short)((u + 0x7fffu + ((u >> 16) & 1u)) >> 16);  // RNE
}

__device__ __forceinline__ float bf2f(unsigned short u) {
    return __uint_as_float((unsigned)u << 16);
}

__device__ __forceinline__ unsigned pk2(float a, float b) {
    union { __hip_bfloat162 h2; unsigned u; } cv;
    cv.h2 = __float22bfloat162_rn(float2{a, b});   // low 16 = a (RNE)
    return cv.u;
}

__device__ __forceinline__ bf16x8 u4bf8(uint4 u) {   // scalar union: SROA-safe
    union { uint4 a; bf16x8 b; } cv; cv.a = u; return cv.b;
}

// ---------------------------------------------------------------------------
// KBW (merged): blocks [0,2048) = adj -> 64-bit masks (proven R8 kb);
//               blocks [2048,2112) = W fp32 -> WT[h][o][k] bf16 (proven kw).
// kw's 9 KB LDS does NOT cap kb residency (17 blocks/CU > needed 8) — unlike
// R9's 27 KB fusion. Phases touch disjoint data; no ordering needed.
// ---------------------------------------------------------------------------
__global__ __launch_bounds__(256) void kbw(const int* __restrict__ adj,
                                           const float* __restrict__ W,
                                           unsigned long long* __restrict__ bits,
                                           unsigned short* __restrict__ WT) {
    __shared__ unsigned short T[64][72];
    const int t = threadIdx.x;
    if (blockIdx.x < 2048) {
        const int wv   = blockIdx.x * 4 + (t >> 6);
        const int lane = t & 63;
        const int base = wv * 32;
        #pragma unroll
        for (int r = 0; r < 4; ++r) {
            int v0 = adj[(size_t)(base + r*8 + 0) * 64 + lane];
            int v1 = adj[(size_t)(base + r*8 + 1) * 64 + lane];
            int v2 = adj[(size_t)(base + r*8 + 2) * 64 + lane];
            int v3 = adj[(size_t)(base + r*8 + 3) * 64 + lane];
            int v4 = adj[(size_t)(base + r*8 + 4) * 64 + lane];
            int v5 = adj[(size_t)(base + r*8 + 5) * 64 + lane];
            int v6 = adj[(size_t)(base + r*8 + 6) * 64 + lane];
            int v7 = adj[(size_t)(base + r*8 + 7) * 64 + lane];
            unsigned long long m0 = __ballot(v0 > 0);
            unsigned long long m1 = __ballot(v1 > 0);
            unsigned long long m2 = __ballot(v2 > 0);
            unsigned long long m3 = __ballot(v3 > 0);
            unsigned long long m4 = __ballot(v4 > 0);
            unsigned long long m5 = __ballot(v5 > 0);
            unsigned long long m6 = __ballot(v6 > 0);
            unsigned long long m7 = __ballot(v7 > 0);
            if (lane == 0) {
                ulonglong2* dst = (ulonglong2*)&bits[base + r*8];
                dst[0] = {m0, m1};
                dst[1] = {m2, m3};
                dst[2] = {m4, m5};
                dst[3] = {m6, m7};
            }
        }
        return;
    }
    // ---- kw phase ----
    const int bx = blockIdx.x - 2048;        // 0..63
    const int h  = bx >> 3;
    const int k0 = (bx & 7) * 64;
    #pragma unroll
    for (int i = 0; i < 4; ++i) {
        int idx = t + i * 256;               // 0..1023: kk 0..63 x o4 0..15
        int kk = idx >> 4, o4 = (idx & 15) * 4;
        float4 v = *(const float4*)&W[((size_t)h * FIN + k0 + kk) * FOUT + o4];
        T[o4+0][kk] = f2bf(v.x); T[o4+1][kk] = f2bf(v.y);
        T[o4+2][kk] = f2bf(v.z); T[o4+3][kk] = f2bf(v.w);
    }
    __syncthreads();
    #pragma unroll
    for (int i = 0; i < 2; ++i) {
        int c = t + i * 256;                 // 0..511: o = c>>3, kch = (c&7)*8
        int o = c >> 3, kch = (c & 7) * 8;
        *(uint4*)&WT[((size_t)h * 64 + o) * FIN + k0 + kch] =
            *(const uint4*)&T[o][kch];
    }
}

// ---------------------------------------------------------------------------
// KG: Wh = x @ W via bf16 MFMA, zero staging LDS. (R19 split geometry,
// 1024 blocks x 128 thr, unchanged.)
// ---------------------------------------------------------------------------
__global__ __launch_bounds__(128) void kg(const float* __restrict__ x,
                                          const unsigned short* __restrict__ WT,
                                          const float* __restrict__ aw,
                                          unsigned short* __restrict__ WhTs,
                                          float* __restrict__ f1,
                                          float* __restrict__ f2) {
    __shared__ unsigned short Tb[64][40];   // [o][local row 0..31]
    __shared__ float r1[32][16];
    __shared__ float r2[32][16];
    const int t = threadIdx.x, lane = t & 63, wid = t >> 6;   // 2 waves
    const int bx   = blockIdx.x;              // 0..1023
    const int h    = bx >> 7;
    const int sub  = bx & 127;
    const int nti  = sub >> 1;                // WhTs tile 0..63
    const int half = sub & 1;                 // which 32-row half
    const int row0 = nti * 64 + half * 32;
    const int lrow = wid * 16 + (lane & 15);  // local row 0..31
    const int kc   = (lane >> 4) * 8;         // k-chunk within 32-step
    const float* xr = x + (size_t)(row0 + lrow) * FIN;
    const unsigned short* WTh = WT + (size_t)h * 64 * FIN;
    f32x4 acc[4] = {};

    #pragma unroll 4
    for (int k0 = 0; k0 < FIN; k0 += 32) {
        float4 xa = *(const float4*)&xr[k0 + kc];
        float4 xb = *(const float4*)&xr[k0 + kc + 4];
        bf16x8 af = u4bf8(uint4{pk2(xa.x, xa.y), pk2(xa.z, xa.w),
                                pk2(xb.x, xb.y), pk2(xb.z, xb.w)});
        #pragma unroll
        for (int cf = 0; cf < 4; ++cf) {
            int o = cf * 16 + (lane & 15);
            bf16x8 bfr = *(const bf16x8*)&WTh[(size_t)o * FIN + k0 + kc];
            acc[cf] = __builtin_amdgcn_mfma_f32_16x16x32_bf16(af, bfr, acc[cf], 0, 0, 0);
        }
    }

    // epilogue: f1/f2 partials + bf16 transpose tile (from C-layout accs)
    float a1v[4], a2v[4];
    #pragma unroll
    for (int cf = 0; cf < 4; ++cf) {
        a1v[cf] = aw[h * 2 * FOUT + cf * 16 + (lane & 15)];
        a2v[cf] = aw[h * 2 * FOUT + FOUT + cf * 16 + (lane & 15)];
    }
    #pragma unroll
    for (int rg = 0; rg < 4; ++rg) {
        const int lr = wid * 16 + (lane >> 4) * 4 + rg;   // local C row 0..31
        float s1 = 0.f, s2 = 0.f;
        #pragma unroll
        for (int cf = 0; cf < 4; ++cf) {
            s1 = fmaf(acc[cf][rg], a1v[cf], s1);
            s2 = fmaf(acc[cf][rg], a2v[cf], s2);
            Tb[cf * 16 + (lane & 15)][lr] = f2bf(acc[cf][rg]);
        }
        r1[lr][lane & 15] = s1;
        r2[lr][lane & 15] = s2;
    }
    __syncthreads();
    if (t < 32) {
        float s1 = 0.f, s2 = 0.f;
        #pragma unroll
        for (int k = 0; k < 16; ++k) { s1 += r1[t][k]; s2 += r2[t][k]; }
        f1[h * NN + row0 + t] = s1 * LOG2E;   // prescale: exp(x)=exp2(x*log2e)
        f2[h * NN + row0 + t] = s2 * LOG2E;
    }
    // write this half's chunks of the tile in k3's swizzled byte order
    unsigned char* tileB = (unsigned char*)(WhTs + ((size_t)(h * 64) + nti) * 4096);
    #pragma unroll
    for (int i = 0; i < 2; ++i) {
        int c = t + i * 128;                 // 0..255: o = c>>2, q = c&3
        int o = c >> 2, q = c & 3;
        *(uint4*)(tileB + o * 128 + (((half * 64 + q * 16)) ^ ((o & 7) << 4))) =
            *(const uint4*)&Tb[o][q * 8];
    }
}

// ---------------------------------------------------------------------------
// K3: fused masked softmax + PV (bf16 MFMA), j-split. R18 structure; only
// change: pnum partials stored as bf16 (halves k3 WRITE + k4 FETCH; den
// stays fp32 so output error stays ~0.2% of num — well within threshold).
// ---------------------------------------------------------------------------
__global__ __launch_bounds__(256, 4) void k3_attn(
        const unsigned long long* __restrict__ bits,
        const unsigned short* __restrict__ WhTs,
        const float* __restrict__ f1, const float* __restrict__ f2,
        unsigned short* __restrict__ pnum, float* __restrict__ pden) {
    __shared__ unsigned char psB[ROWS * 128];   // 16 KB
    __shared__ unsigned char wsB[8192];         //  8 KB
    const int t    = threadIdx.x;
    const int lane = t & 63, wid = t >> 6;
    const int h    = blockIdx.y;
    const int row0 = blockIdx.x * ROWS;
    const int js   = blockIdx.z, JS = gridDim.z;
    const int ntile = (NN / 64) / JS;
    const int nt0   = js * ntile;
    const int pr   = t >> 1, psub = t & 1;     // row 0..127, j-half 0..1
    const float f1r = f1[h * NN + row0 + pr];
    const float* f2h = f2 + h * NN;
    const unsigned long long* bitsRow = bits + (size_t)(row0 + pr) * 64;
    const unsigned short* WTS = WhTs + (size_t)h * 64 * 4096;
    const int prswz = (pr & 7) << 4;
    f32x4 acc[2][4] = {};
    f32x4 accd[2] = {};
    const bf16x8 ones = {0x3F80, 0x3F80, 0x3F80, 0x3F80,
                         0x3F80, 0x3F80, 0x3F80, 0x3F80};   // bf16 1.0 x8
    const f32x2 f1p = {f1r, f1r};

    uint4 wreg0, wreg1;
    auto loadW = [&](int nti, uint4& w0, uint4& w1) {
        const uint4* gt = (const uint4*)(WTS + (size_t)nti * 4096);
        w0 = gt[t];
        w1 = gt[t + 256];
    };
    loadW(nt0, wreg0, wreg1);

    const int kb2 = (lane >> 4) * 16;
    for (int it = 0; it < ntile; ++it) {
        const int nti = nt0 + it;
        __syncthreads();                       // prev MFMA done reading tiles
        *(uint4*)&wsB[t * 16]        = wreg0;
        *(uint4*)&wsB[t * 16 + 4096] = wreg1;
        {
            unsigned msk = (unsigned)(bitsRow[nti] >> (psub << 5));
            const float* f2c = f2h + nti * 64 + psub * 32;
            #pragma unroll
            for (int q = 0; q < 4; ++q) {
                unsigned pk[4];
                #pragma unroll
                for (int c2 = 0; c2 < 2; ++c2) {
                    float4 f4 = *(const float4*)&f2c[q * 8 + c2 * 4];
                    f32x2 eA = f1p + (f32x2){f4.x, f4.y};   // v_pk_add_f32
                    f32x2 eB = f1p + (f32x2){f4.z, f4.w};
                    eA = __builtin_elementwise_max(eA, eA * ALPHA);  // pk_mul+pk_max
                    eB = __builtin_elementwise_max(eB, eB * ALPHA);
                    const int b = q * 8 + c2 * 4;
                    float p0 = ((msk >> (b+0)) & 1u) ? __builtin_amdgcn_exp2f(eA.x) : 0.f;
                    float p1 = ((msk >> (b+1)) & 1u) ? __builtin_amdgcn_exp2f(eA.y) : 0.f;
                    float p2 = ((msk >> (b+2)) & 1u) ? __builtin_amdgcn_exp2f(eB.x) : 0.f;
                    float p3 = ((msk >> (b+3)) & 1u) ? __builtin_amdgcn_exp2f(eB.y) : 0.f;
                    pk[c2*2+0] = pk2(p0, p1);
                    pk[c2*2+1] = pk2(p2, p3);
                }
                uint4 w = {pk[0], pk[1], pk[2], pk[3]};
                *(uint4*)&psB[pr * 128 + ((psub*64 + q*16) ^ prswz)] = w;
            }
        }
        if (it + 1 < ntile) loadW(nti + 1, wreg0, wreg1);
        __syncthreads();                       // tiles visible
        #pragma unroll
        for (int fg = 0; fg < 2; ++fg) {
            const int arw  = wid * 32 + fg * 16 + (lane & 15);
            const int aswz = (arw & 7) << 4;
            #pragma unroll
            for (int ks = 0; ks < 2; ++ks) {
                bf16x8 af = *(const bf16x8*)&psB[arw * 128 + ((ks*64 + kb2) ^ aswz)];
                accd[fg] = __builtin_amdgcn_mfma_f32_16x16x32_bf16(af, ones, accd[fg], 0, 0, 0);
                #pragma unroll
                for (int cf = 0; cf < 4; ++cf) {
                    int brw = cf * 16 + (lane & 15);
                    bf16x8 bfr = *(const bf16x8*)&wsB[brw * 128 + ((ks*64 + kb2) ^ ((brw & 7) << 4))];
                    acc[fg][cf] = __builtin_amdgcn_mfma_f32_16x16x32_bf16(af, bfr, acc[fg][cf], 0, 0, 0);
                }
            }
        }
    }

    unsigned short* pn = pnum + (((size_t)js * NH + h) * NN + row0) * 64;
    #pragma unroll
    for (int fg = 0; fg < 2; ++fg)
        #pragma unroll
        for (int cf = 0; cf < 4; ++cf) {
            int o = cf * 16 + (lane & 15);
            #pragma unroll
            for (int rg = 0; rg < 4; ++rg) {
                int rl = wid * 32 + fg * 16 + (lane >> 4) * 4 + rg;
                pn[(size_t)rl * 64 + o] = f2bf(acc[fg][cf][rg]);
            }
        }
    if ((lane & 15) == 0) {                    // col-0 lanes hold den[row]
        float* pd = pden + ((size_t)js * NH + h) * NN + row0;
        #pragma unroll
        for (int fg = 0; fg < 2; ++fg)
            #pragma unroll
            for (int rg = 0; rg < 4; ++rg)
                pd[wid * 32 + fg * 16 + (lane >> 4) * 4 + rg] = accd[fg][rg];
    }
}

// ---------------------------------------------------------------------------
// K4: reduce over JS slices (bf16 partials) + normalize.
// ---------------------------------------------------------------------------
__global__ __launch_bounds__(256) void k4_red(const unsigned short* __restrict__ pnum,
                                              const float* __restrict__ pden,
                                              float* __restrict__ out, int JS) {
    const int idx = blockIdx.x * 256 + threadIdx.x;   // 0..524287
    const int h   = idx >> 16;
    const int rem = idx & 65535;
    const int n   = rem >> 4;
    const int o4  = (rem & 15) * 4;
    float4 s = {0.f, 0.f, 0.f, 0.f};
    float  d = 0.f;
    for (int js = 0; js < JS; ++js) {
        const ushort4 v = *(const ushort4*)(pnum + (((size_t)js * NH + h) * NN + n) * 64 + o4);
        s.x += bf2f(v.x); s.y += bf2f(v.y); s.z += bf2f(v.z); s.w += bf2f(v.w);
        d += pden[((size_t)js * NH + h) * NN + n];
    }
    float inv = 1.0f / d;
    float4 r = {s.x * inv, s.y * inv, s.z * inv, s.w * inv};
    *(float4*)&out[(size_t)n * (NH * FOUT) + h * FOUT + o4] = r;
}

extern "C" void kernel_launch(void* const* d_in, const int* in_sizes, int n_in,
                              void* d_out, int out_size, void* d_ws, size_t ws_size,
                              hipStream_t stream) {
    const float* x   = (const float*)d_in[0];
    const int*   adj = (const int*)d_in[1];
    const float* W   = (const float*)d_in[2];
    const float* a   = (const float*)d_in[3];
    float* outp = (float*)d_out;

    // workspace layout
    unsigned short* WhTs = (unsigned short*)d_ws;                   // 4 MB (tiled)
    float* f1 = (float*)(WhTs + (size_t)NH * 64 * NN);              // 128 KB
    float* f2 = f1 + NH * NN;                                       // 128 KB
    unsigned short* WT = (unsigned short*)(f2 + NH * NN);           // 512 KB bf16
    unsigned long long* bits = (unsigned long long*)(WT + (size_t)NH * 64 * FIN); // 2 MB
    unsigned short* pnum = (unsigned short*)(bits + (size_t)NN * 64);
    const size_t baseBytes  = (size_t)((char*)pnum - (char*)d_ws);
    const size_t sliceBytes = (size_t)NH * NN * (64 * 2 + 4);       // bf16 num + f32 den
    int JS = 1;
    if      (ws_size >= baseBytes + 4 * sliceBytes) JS = 4;
    else if (ws_size >= baseBytes + 2 * sliceBytes) JS = 2;
    float* pden = (float*)(pnum + (size_t)JS * NH * NN * 64);

    kbw    <<<dim3(2048 + 64),       256, 0, stream>>>(adj, W, bits, WT);
    kg     <<<dim3(1024),            128, 0, stream>>>(x, WT, a, WhTs, f1, f2);
    k3_attn<<<dim3(NN/ROWS, NH, JS), 256, 0, stream>>>(bits, WhTs, f1, f2, pnum, pden);
    k4_red <<<dim3(NN*NH*FOUT/4/256), 256, 0, stream>>>(pnum, pden, outp, JS);
}